// Round 3
// baseline (324.523 us; speedup 1.0000x reference)
//
#include <hip/hip_runtime.h>
#include <stdint.h>

// Problem constants (reference: N=2048, M=100000, D=128, K=5)
#define N_Q 2048
#define M_B 100000
#define D_DIM 128
#define KNN 5
#define SLABS_TOTAL 1563            // ceil(M/64)
#define M_PAD (SLABS_TOTAL * 64)    // 100032
#define CHUNKS 61
#define SPC 26                      // slabs per chunk; EVEN so slab-pairs never span chunks
#define PAIRS_TOTAL 782             // ceil(1563/2); pair p = slabs {2p, 2p+1}
#define ROWBLOCKS 16
#define TROWS 128
#define CAP_P 24                    // surviving pairs per row (E~7, P(>24) negligible)
#define CAP_C 32                    // candidate d2 per row (E~7)
#define EPSA 1.5f                   // acc-space consistency margin (~10 sigma of bf16 err)
#define BIGF 3.0e38f
#define NEGF -3.0e38f

typedef __attribute__((ext_vector_type(8))) short short8;      // MFMA A/B frag (8 bf16)
typedef __attribute__((ext_vector_type(4))) unsigned short ushort4v;
typedef __attribute__((ext_vector_type(8))) unsigned short ushort8v;
typedef __attribute__((ext_vector_type(4))) float f32x4;       // MFMA C/D frag

static __device__ __forceinline__ unsigned short f2bf(float f) {
  unsigned int u = __builtin_bit_cast(unsigned int, f);
  u = (u + 0x7FFFu + ((u >> 16) & 1u)) >> 16;   // RNE
  return (unsigned short)u;
}
static __device__ __forceinline__ float bf2f(unsigned short u) {
  return __builtin_bit_cast(float, ((unsigned int)u) << 16);
}

static __device__ __forceinline__ void gload_lds16(const void* g, void* l) {
  __builtin_amdgcn_global_load_lds((const __attribute__((address_space(1))) unsigned int*)g,
                                   (__attribute__((address_space(3))) unsigned int*)l, 16, 0, 0);
}
static __device__ __forceinline__ void gload_lds4(const void* g, void* l) {
  __builtin_amdgcn_global_load_lds((const __attribute__((address_space(1))) unsigned int*)g,
                                   (__attribute__((address_space(3))) unsigned int*)l, 4, 0, 0);
}

// max-reduce v across the 16 contiguous lanes of a DPP row, pure VALU:
// xor1 (quad_perm [1,0,3,2]=0xB1), xor2 (quad_perm [2,3,0,1]=0x4E),
// cross-quad (row_half_mirror=0x141), cross-8 (row_mirror=0x140).
#define DPPMAX(v, ctrl)                                                              \
  do {                                                                               \
    int _t = __builtin_amdgcn_update_dpp(0, __builtin_bit_cast(int, (v)), (ctrl),    \
                                         0xf, 0xf, false);                           \
    (v) = fmaxf((v), __builtin_bit_cast(float, _t));                                 \
  } while (0)

// ---------------------------------------------------------------------------
// K0: bank fp32 -> bf16 slab-tiled + ny2 = -0.5*|y|^2 (pads NEGF).
// Reads coalesced; bf16 tile staged in LDS so GLOBAL writes are coalesced
// 16B/lane (R2's scattered 8B stores were ~5x HBM write amplification).
// Tiled layout: slab s, unit u = kc*64 + j holds Y[s*64+j][kc*8 .. kc*8+8).
// ---------------------------------------------------------------------------
__global__ __launch_bounds__(256) void k_prep(const float* __restrict__ Y,
                                              unsigned short* __restrict__ ybf,
                                              float* __restrict__ ny2) {
  const int s = blockIdx.x;
  const int t = threadIdx.x;
  __shared__ __align__(16) unsigned short tile[8192];   // 16 KB bf16 slab
  __shared__ float redy[64 * 33];
#pragma unroll
  for (int i = 0; i < 8; ++i) {
    const int u = i * 256 + t;
    const int rowl = u >> 5;                     // 0..63
    const int q = u & 31;                        // float4 index in row
    const int rowg = s * 64 + rowl;
    const int rowc = (rowg < M_B) ? rowg : (M_B - 1);
    const float4 v = ((const float4*)Y)[(size_t)rowc * 32 + q];
    redy[rowl * 33 + q] = v.x * v.x + v.y * v.y + v.z * v.z + v.w * v.w;
    ushort4v o;
    o[0] = f2bf(v.x); o[1] = f2bf(v.y); o[2] = f2bf(v.z); o[3] = f2bf(v.w);
    *(ushort4v*)(tile + (size_t)(((q >> 1) * 64 + rowl) * 8 + (q & 1) * 4)) = o;
  }
  __syncthreads();
#pragma unroll
  for (int i = 0; i < 4; ++i) {                  // coalesced 16B/lane global writes
    const int u = i * 256 + t;
    *(ushort8v*)(ybf + ((size_t)s * 1024 + u) * 8) = *(const ushort8v*)(tile + u * 8);
  }
  if (t < 64) {
    float sum = 0.f;
#pragma unroll
    for (int j = 0; j < 32; ++j) sum += redy[t * 33 + j];
    const int rowg = s * 64 + t;
    ny2[(size_t)s * 64 + t] = (rowg < M_B) ? (-0.5f * sum) : NEGF;
  }
}

// ---------------------------------------------------------------------------
// Main (single MFMA pass): block = 128 rows x one chunk (26 slabs).
// acc = dot - 0.5*(x2+y2); per (row, slab-PAIR) max -> rsm via DPP reduction.
// MFMA layouts (verified m89/m91): A[m=lane&15][k=(lane>>4)*8+j],
// B[n=lane&15][k=(lane>>4)*8+j], C/D col=lane&15 row=(lane>>4)*4+reg.
// ---------------------------------------------------------------------------
__global__ __launch_bounds__(256, 4) void k_main(const float* __restrict__ X,
                                                 const unsigned short* __restrict__ ybf,
                                                 const float* __restrict__ ny2,
                                                 float* __restrict__ rsm) {
  __shared__ __align__(16) char smem[16640];
  unsigned short* ys = (unsigned short*)smem;        // 16384: bf16 slab
  float* ny2s = (float*)(smem + 16384);              //   256

  const int bid = blockIdx.x;
  const int chunk = bid >> 4;                        // 0..60
  const int rowblock = bid & 15;
  const int row0 = rowblock * TROWS;

  const int cs0 = chunk * SPC;                       // even
  int nslab = SLABS_TOTAL - cs0;
  if (nslab > SPC) nslab = SPC;

  const int t = threadIdx.x;
  const int wave = t >> 6;
  const int lane = t & 63;
  const int lm = lane & 15;
  const int lq = lane >> 4;

  // ---- nx2 = -0.5*|x|^2 per accumulator row (fp32 exact) ----
  float nx2r[2][4];
  {
    float* red = (float*)smem;                       // pre-loop overlay
    const int r = t >> 1, h = t & 1;
    const float4* xp = (const float4*)(X + (size_t)(row0 + r) * D_DIM + h * 64);
    float ss = 0.f;
#pragma unroll
    for (int i = 0; i < 16; ++i) {
      const float4 v = xp[i];
      ss += v.x * v.x + v.y * v.y + v.z * v.z + v.w * v.w;
    }
    red[t] = ss;
    __syncthreads();
#pragma unroll
    for (int rt = 0; rt < 2; ++rt)
#pragma unroll
      for (int rr = 0; rr < 4; ++rr) {
        const int rl = wave * 32 + rt * 16 + lq * 4 + rr;
        nx2r[rt][rr] = -0.5f * (red[rl * 2] + red[rl * 2 + 1]);
      }
    __syncthreads();
  }

  // ---- A fragments resident in registers (bf16) ----
  short8 afrag[2][4];
#pragma unroll
  for (int rt = 0; rt < 2; ++rt)
#pragma unroll
    for (int ks = 0; ks < 4; ++ks) {
      const float* xr = X + (size_t)(row0 + wave * 32 + rt * 16 + lm) * D_DIM + ks * 32 + lq * 8;
      const float4 a = *(const float4*)xr;
      const float4 b = *(const float4*)(xr + 4);
      short8 f;
      f[0] = (short)f2bf(a.x); f[1] = (short)f2bf(a.y);
      f[2] = (short)f2bf(a.z); f[3] = (short)f2bf(a.w);
      f[4] = (short)f2bf(b.x); f[5] = (short)f2bf(b.y);
      f[6] = (short)f2bf(b.z); f[7] = (short)f2bf(b.w);
      afrag[rt][ks] = f;
    }

  float runmax[2][4];
#pragma unroll
  for (int rt = 0; rt < 2; ++rt)
#pragma unroll
    for (int rr = 0; rr < 4; ++rr) runmax[rt][rr] = NEGF;

  for (int s = 0; s < nslab; ++s) {
    const int sg = cs0 + s;
    const unsigned short* src = ybf + (size_t)sg * 8192;
#pragma unroll
    for (int i = 0; i < 4; ++i) {
      const int ub = i * 256 + wave * 64;
      gload_lds16(src + (size_t)(ub + lane) * 8, ys + (size_t)ub * 8);
    }
    if (wave == 0) gload_lds4(ny2 + (size_t)sg * 64 + lane, ny2s);
    __syncthreads();

    float y2c[4];
#pragma unroll
    for (int ct = 0; ct < 4; ++ct) y2c[ct] = ny2s[ct * 16 + lm];

    f32x4 acc[2][4];
#pragma unroll
    for (int rt = 0; rt < 2; ++rt)
#pragma unroll
      for (int ct = 0; ct < 4; ++ct)
#pragma unroll
        for (int rr = 0; rr < 4; ++rr) acc[rt][ct][rr] = nx2r[rt][rr] + y2c[ct];

#pragma unroll
    for (int ct = 0; ct < 4; ++ct) {
      short8 bfr[4];
#pragma unroll
      for (int ks = 0; ks < 4; ++ks)
        bfr[ks] = *(const short8*)(ys + (size_t)(((ks * 4 + lq) * 64 + ct * 16 + lm)) * 8);
#pragma unroll
      for (int rt = 0; rt < 2; ++rt)
#pragma unroll
        for (int ks = 0; ks < 4; ++ks)
          acc[rt][ct] = __builtin_amdgcn_mfma_f32_16x16x32_bf16(afrag[rt][ks], bfr[ks],
                                                                acc[rt][ct], 0, 0, 0);
    }

    // ---- running per-(row, pair) max; flush via DPP every 2nd slab ----
#pragma unroll
    for (int rt = 0; rt < 2; ++rt)
#pragma unroll
      for (int rr = 0; rr < 4; ++rr) {
        const float mx = fmaxf(fmaxf(acc[rt][0][rr], acc[rt][1][rr]),
                               fmaxf(acc[rt][2][rr], acc[rt][3][rr]));
        runmax[rt][rr] = fmaxf(runmax[rt][rr], mx);
      }
    if ((sg & 1) || (s == nslab - 1)) {
      const int pairidx = sg >> 1;
#pragma unroll
      for (int rt = 0; rt < 2; ++rt)
#pragma unroll
        for (int rr = 0; rr < 4; ++rr) {
          float v = runmax[rt][rr];
          DPPMAX(v, 0xB1);   // xor1
          DPPMAX(v, 0x4E);   // xor2
          DPPMAX(v, 0x141);  // row_half_mirror (cross-quad)
          DPPMAX(v, 0x140);  // row_mirror (cross-8) -> 16-lane max
          if (lm == 0) {
            const int rowg = row0 + wave * 32 + rt * 16 + lq * 4 + rr;
            rsm[(size_t)rowg * PAIRS_TOTAL + pairidx] = v;
          }
          runmax[rt][rr] = NEGF;
        }
    }
    __syncthreads();   // WAR before restage
  }
}

// ---------------------------------------------------------------------------
// K_mid: one wave per row. T = 5th largest of the row's 782 pair maxima
// (valid: 5 distinct pairs => >=5 columns with acc >= T). Survivors:
// pairs with max >= T - 2*EPSA. Also emits d2 threshold for pass 2.
// ---------------------------------------------------------------------------
__global__ __launch_bounds__(256) void k_mid(const float* __restrict__ rsm,
                                             float* __restrict__ d2thr,
                                             int* __restrict__ scnt,
                                             int* __restrict__ slist) {
  __shared__ float lt[4][64][5];
  __shared__ int lcnt[4];
  const int wave = threadIdx.x >> 6;
  const int lane = threadIdx.x & 63;
  const int row = blockIdx.x * 4 + wave;
  const float* rp = rsm + (size_t)row * PAIRS_TOTAL;

  float b0 = NEGF, b1 = NEGF, b2 = NEGF, b3 = NEGF, b4 = NEGF;  // descending
  for (int p = lane; p < PAIRS_TOTAL; p += 64) {
    const float v = rp[p];
    if (v > b4) {
      float m = v;
      float n3 = fminf(b3, m); m = fmaxf(b3, m);
      float n2 = fminf(b2, m); m = fmaxf(b2, m);
      float n1 = fminf(b1, m); m = fmaxf(b1, m);
      float n0 = fminf(b0, m); m = fmaxf(b0, m);
      b0 = m; b1 = n0; b2 = n1; b3 = n2; b4 = n3;
    }
  }
  lt[wave][lane][0] = b0; lt[wave][lane][1] = b1; lt[wave][lane][2] = b2;
  lt[wave][lane][3] = b3; lt[wave][lane][4] = b4;
  if (lane == 0) lcnt[wave] = 0;
  __syncthreads();

  float Tv = NEGF;
  if (lane == 0) {
    float c0 = NEGF, c1 = NEGF, c2 = NEGF, c3 = NEGF, c4 = NEGF;
    for (int l = 0; l < 64; ++l)
#pragma unroll
      for (int j = 0; j < 5; ++j) {
        const float v = lt[wave][l][j];
        if (v > c4) {
          float m = v;
          float n3 = fminf(c3, m); m = fmaxf(c3, m);
          float n2 = fminf(c2, m); m = fmaxf(c2, m);
          float n1 = fminf(c1, m); m = fmaxf(c1, m);
          float n0 = fminf(c0, m); m = fmaxf(c0, m);
          c0 = m; c1 = n0; c2 = n1; c3 = n2; c4 = n3;
        }
      }
    Tv = c4;
  }
  Tv = __shfl(Tv, 0);
  const float thr = Tv - 2.0f * EPSA;
  if (lane == 0) d2thr[row] = -2.0f * thr;

  for (int p = lane; p < PAIRS_TOTAL; p += 64) {
    if (rp[p] >= thr) {
      const int pos = atomicAdd(&lcnt[wave], 1);
      if (pos < CAP_P) slist[row * CAP_P + pos] = p;
    }
  }
  __syncthreads();
  if (lane == 0) scnt[row] = (lcnt[wave] < CAP_P) ? lcnt[wave] : CAP_P;
}

// ---------------------------------------------------------------------------
// K_pass2: one wave per (row, surviving pair). fp32-exact d2 = |x - ybf|^2
// for the pair's 128 columns from the bf16 tiled bank (coalesced 1KB loads;
// X loads are wave-uniform -> broadcast). Collect d2 <= d2thr into cand.
// ---------------------------------------------------------------------------
__global__ __launch_bounds__(256) void k_pass2(const float* __restrict__ X,
                                               const unsigned short* __restrict__ ybf,
                                               const float* __restrict__ d2thr,
                                               const int* __restrict__ scnt,
                                               const int* __restrict__ slist,
                                               int* __restrict__ ccnt,
                                               float* __restrict__ cand) {
  const int wave = threadIdx.x >> 6;
  const int lane = threadIdx.x & 63;
  const int gid = blockIdx.x * 4 + wave;
  const int row = gid / CAP_P;
  const int i = gid - row * CAP_P;
  if (row >= N_Q) return;
  if (i >= scnt[row]) return;

  const int p = slist[row * CAP_P + i];
  const float thr = d2thr[row];
  const float* xr = X + (size_t)row * D_DIM;

#pragma unroll
  for (int sl = 0; sl < 2; ++sl) {
    const int slab = 2 * p + sl;
    if (slab >= SLABS_TOTAL) break;
    const int col = slab * 64 + lane;
    const unsigned short* yb = ybf + (size_t)slab * 8192 + lane * 8;
    float xy = 0.f, yy = 0.f, xx = 0.f;
#pragma unroll
    for (int kc = 0; kc < 16; ++kc) {
      const ushort8v y8 = *(const ushort8v*)(yb + kc * 512);
      const float4 xa = *(const float4*)(xr + kc * 8);
      const float4 xb = *(const float4*)(xr + kc * 8 + 4);
      const float y0 = bf2f(y8[0]), y1 = bf2f(y8[1]), y2v = bf2f(y8[2]), y3 = bf2f(y8[3]);
      const float y4 = bf2f(y8[4]), y5 = bf2f(y8[5]), y6 = bf2f(y8[6]), y7 = bf2f(y8[7]);
      xy = fmaf(xa.x, y0, xy); xy = fmaf(xa.y, y1, xy);
      xy = fmaf(xa.z, y2v, xy); xy = fmaf(xa.w, y3, xy);
      xy = fmaf(xb.x, y4, xy); xy = fmaf(xb.y, y5, xy);
      xy = fmaf(xb.z, y6, xy); xy = fmaf(xb.w, y7, xy);
      yy = fmaf(y0, y0, yy); yy = fmaf(y1, y1, yy);
      yy = fmaf(y2v, y2v, yy); yy = fmaf(y3, y3, yy);
      yy = fmaf(y4, y4, yy); yy = fmaf(y5, y5, yy);
      yy = fmaf(y6, y6, yy); yy = fmaf(y7, y7, yy);
      xx = fmaf(xa.x, xa.x, xx); xx = fmaf(xa.y, xa.y, xx);
      xx = fmaf(xa.z, xa.z, xx); xx = fmaf(xa.w, xa.w, xx);
      xx = fmaf(xb.x, xb.x, xx); xx = fmaf(xb.y, xb.y, xx);
      xx = fmaf(xb.z, xb.z, xx); xx = fmaf(xb.w, xb.w, xx);
    }
    const float d2 = fmaxf(xx + yy - 2.f * xy, 0.f);
    if (col < M_B && d2 <= thr) {
      const int pos = atomicAdd(&ccnt[row], 1);
      if (pos < CAP_C) cand[(size_t)row * CAP_C + pos] = d2;
    }
  }
}

// ---------------------------------------------------------------------------
// K_final: per row top-5 smallest of candidates -> sqrt, mean, normalize
// ---------------------------------------------------------------------------
__global__ __launch_bounds__(256) void k_final(const float* __restrict__ cand,
                                               const int* __restrict__ ccnt,
                                               const float* __restrict__ minp,
                                               const float* __restrict__ maxp,
                                               float* __restrict__ out) {
  const int row = blockIdx.x * 256 + threadIdx.x;
  if (row >= N_Q) return;
  int c = ccnt[row];
  if (c > CAP_C) c = CAP_C;
  const float* cp = cand + (size_t)row * CAP_C;
  float b0 = BIGF, b1 = BIGF, b2 = BIGF, b3 = BIGF, b4 = BIGF;  // ascending
  for (int i = 0; i < c; ++i) {
    const float v = cp[i];
    if (v < b4) {
      float m = v;
      float n3 = fmaxf(b3, m); m = fminf(b3, m);
      float n2 = fmaxf(b2, m); m = fminf(b2, m);
      float n1 = fmaxf(b1, m); m = fminf(b1, m);
      float n0 = fmaxf(b0, m); m = fminf(b0, m);
      b0 = m; b1 = n0; b2 = n1; b3 = n2; b4 = n3;
    }
  }
  const float s = sqrtf(b0) + sqrtf(b1) + sqrtf(b2) + sqrtf(b3) + sqrtf(b4);
  const float mn = minp[0], mx = maxp[0];
  out[row] = (s * (1.0f / KNN) - mn) / (mx - mn);
}

extern "C" void kernel_launch(void* const* d_in, const int* in_sizes, int n_in,
                              void* d_out, int out_size, void* d_ws, size_t ws_size,
                              hipStream_t stream) {
  const float* X = (const float*)d_in[0];
  const float* Y = (const float*)d_in[1];
  const float* minp = (const float*)d_in[2];
  const float* maxp = (const float*)d_in[3];
  float* out = (float*)d_out;

  char* ws = (char*)d_ws;
  size_t off = 0;
  unsigned short* ybf = (unsigned short*)(ws + off); off += (size_t)M_PAD * D_DIM * 2;  // 25.6 MB
  float* ny2 = (float*)(ws + off);                   off += (size_t)M_PAD * 4;          // 400 KB
  float* rsm = (float*)(ws + off);                   off += (size_t)N_Q * PAIRS_TOTAL * 4; // 6.4 MB
  float* d2thr = (float*)(ws + off);                 off += (size_t)N_Q * 4;
  int* scnt = (int*)(ws + off);                      off += (size_t)N_Q * 4;
  int* slist = (int*)(ws + off);                     off += (size_t)N_Q * CAP_P * 4;
  int* ccnt = (int*)(ws + off);                      off += (size_t)N_Q * 4;
  float* cand = (float*)(ws + off);                  off += (size_t)N_Q * CAP_C * 4;
  // total ~32.9 MB

  k_prep<<<dim3(SLABS_TOTAL), dim3(256), 0, stream>>>(Y, ybf, ny2);
  hipMemsetAsync(ccnt, 0, (size_t)N_Q * 4, stream);
  k_main<<<dim3(ROWBLOCKS * CHUNKS), dim3(256), 0, stream>>>(X, ybf, ny2, rsm);
  k_mid<<<dim3(N_Q / 4), dim3(256), 0, stream>>>(rsm, d2thr, scnt, slist);
  k_pass2<<<dim3(N_Q * CAP_P / 4), dim3(256), 0, stream>>>(X, ybf, d2thr, scnt, slist, ccnt, cand);
  k_final<<<dim3((N_Q + 255) / 256), dim3(256), 0, stream>>>(cand, ccnt, minp, maxp, out);
}